// Round 3
// baseline (915.704 us; speedup 1.0000x reference)
//
#include <hip/hip_runtime.h>

#define DEV __device__ __forceinline__

typedef __attribute__((ext_vector_type(8))) short short8;
typedef __attribute__((ext_vector_type(4))) float floatx4;

constexpr int Tn  = 4096;   // tokens (B*S)
constexpr int Dm  = 2048;   // model dim
constexpr int In  = 1408;   // expert inter dim
constexpr int En  = 8;      // experts
constexpr int SIn = 2816;   // shared inter dim (2*1408)
constexpr int CAP = 10240;  // 8192 pairs + 8*256 padding (segments padded to 256)

// per-kernel grids (256-row M tiles); all divisible by 8 for XCD swizzle
constexpr int RT_H = (CAP / 256) * (In / 128);    // 40*11 = 440 routed h blocks
constexpr int SH_H = (Tn / 256) * (SIn / 128);    // 16*22 = 352 shared h blocks
constexpr int RT_O = (CAP / 256) * (Dm / 256);    // 40*8  = 320 routed o blocks
constexpr int SH_O = (Tn / 256) * (Dm / 256);     // 16*8  = 128 shared o blocks

DEV unsigned short f2bf(float f) {          // fp32 -> bf16 RNE
  unsigned int u = __float_as_uint(f);
  u += 0x7FFF + ((u >> 16) & 1);
  return (unsigned short)(u >> 16);
}

DEV float bf2f(unsigned short u) {
  return __uint_as_float(((unsigned int)u) << 16);
}

DEV void stg(const char* g, char* l) {
  // async global->LDS, 16B/lane; LDS dst = wave-uniform base + lane*16
  __builtin_amdgcn_global_load_lds(
      (const __attribute__((address_space(1))) unsigned int*)g,
      (__attribute__((address_space(3))) unsigned int*)l, 16, 0, 0);
}

DEV unsigned ldsoff(const void* p) {        // generic LDS ptr -> 32-bit LDS byte offset
  return (unsigned)(unsigned long long)(__attribute__((address_space(3))) const char*)p;
}

// bijective XCD-chunked blockIdx swizzle (nwg % 8 == 0)
DEV int xcd_swz(int bid, int nwg) {
  int cpx = nwg >> 3;
  return (bid & 7) * cpx + (bid >> 3);
}

#define BARR()  __builtin_amdgcn_s_barrier()
#define LGKM0() do { asm volatile("s_waitcnt lgkmcnt(0)" ::: "memory"); \
                     __builtin_amdgcn_sched_barrier(0); } while (0)
#define LGKM8() asm volatile("s_waitcnt lgkmcnt(8)" ::: "memory")
#define VMC(n)  asm volatile("s_waitcnt vmcnt(" #n ")" ::: "memory")
#define PRIO(x) __builtin_amdgcn_s_setprio(x)

// inline-asm ds_read_b128 (immediate offsets; ordering via LGKM/VMC + barriers)
#define DSR(dst, addr, OFFSTR) \
  asm volatile("ds_read_b128 %0, %1 offset:" OFFSTR : "=v"(dst) : "v"(addr))

#define RDA_LO(af, a) do { \
  DSR(af[0][0], a, "0");     DSR(af[0][1], a, "1024"); \
  DSR(af[1][0], a, "2048");  DSR(af[1][1], a, "3072"); \
  DSR(af[2][0], a, "4096");  DSR(af[2][1], a, "5120"); \
  DSR(af[3][0], a, "6144");  DSR(af[3][1], a, "7168"); } while (0)
#define RDA_HI(af, a) do { \
  DSR(af[0][0], a, "8192");  DSR(af[0][1], a, "9216"); \
  DSR(af[1][0], a, "10240"); DSR(af[1][1], a, "11264"); \
  DSR(af[2][0], a, "12288"); DSR(af[2][1], a, "13312"); \
  DSR(af[3][0], a, "14336"); DSR(af[3][1], a, "15360"); } while (0)
#define RDB_LO(bf, a) do { \
  DSR(bf[0][0], a, "0");    DSR(bf[0][1], a, "1024"); \
  DSR(bf[1][0], a, "2048"); DSR(bf[1][1], a, "3072"); } while (0)
#define RDB_HI(bf, a) do { \
  DSR(bf[2][0], a, "4096"); DSR(bf[2][1], a, "5120"); \
  DSR(bf[3][0], a, "6144"); DSR(bf[3][1], a, "7168"); } while (0)

// ---------------- merged conversion kernels ----------------

__global__ void convert_all_kernel(const float* __restrict__ x,
                                   const float* __restrict__ sw1,
                                   const float* __restrict__ sw3,
                                   const float* __restrict__ sw2,
                                   unsigned short* __restrict__ Xb,
                                   unsigned short* __restrict__ sw1b,
                                   unsigned short* __restrict__ sw3b,
                                   unsigned short* __restrict__ sw2b) {
  int y = blockIdx.y;
  const float* src; unsigned short* dst; int n4;
  if (y == 0)      { src = x;   dst = Xb;   n4 = Tn * Dm / 4; }
  else if (y == 1) { src = sw1; dst = sw1b; n4 = SIn * Dm / 4; }
  else if (y == 2) { src = sw3; dst = sw3b; n4 = SIn * Dm / 4; }
  else             { src = sw2; dst = sw2b; n4 = Dm * SIn / 4; }
  int i = blockIdx.x * 256 + threadIdx.x;
  if (i >= n4) return;
  float4 v = ((const float4*)src)[i];
  union { unsigned short u[4]; unsigned long long ll; } p;
  p.u[0] = f2bf(v.x); p.u[1] = f2bf(v.y); p.u[2] = f2bf(v.z); p.u[3] = f2bf(v.w);
  *(unsigned long long*)(dst + (long)i * 4) = p.ll;
}

// 64x64-tile transpose+convert: float4 reads, ushort2 packed writes
__global__ void transpose_all_kernel(const float* __restrict__ W1,
                                     const float* __restrict__ W3,
                                     const float* __restrict__ W2,
                                     unsigned short* __restrict__ W1t,
                                     unsigned short* __restrict__ W3t,
                                     unsigned short* __restrict__ W2t) {
  __shared__ float tile[64][65];
  int z = blockIdx.z;
  const float* s0; unsigned short* d0; int R, C;
  if (z == 0)      { s0 = W1; d0 = W1t; R = Dm; C = In; }
  else if (z == 1) { s0 = W3; d0 = W3t; R = Dm; C = In; }
  else             { s0 = W2; d0 = W2t; R = In; C = Dm; }
  int tilesC = C >> 6;
  int tr = (blockIdx.x / tilesC) << 6;
  int tc = (blockIdx.x % tilesC) << 6;
  const float* s = s0 + (long)blockIdx.y * R * C;
  unsigned short* d = d0 + (long)blockIdx.y * R * C;
  int rr = threadIdx.x >> 4, c4 = (threadIdx.x & 15) << 2;   // 16 rows x 16 float4
#pragma unroll
  for (int p = 0; p < 4; p++) {
    float4 v = *(const float4*)&s[(long)(tr + rr + 16 * p) * C + tc + c4];
    tile[rr + 16 * p][c4]     = v.x;
    tile[rr + 16 * p][c4 + 1] = v.y;
    tile[rr + 16 * p][c4 + 2] = v.z;
    tile[rr + 16 * p][c4 + 3] = v.w;
  }
  __syncthreads();
  int oc = threadIdx.x >> 5, i2 = (threadIdx.x & 31) << 1;   // 8 out-rows x 32 pairs
#pragma unroll
  for (int p = 0; p < 8; p++) {
    int j = oc + 8 * p;
    union { unsigned short u[2]; unsigned int w; } pk;
    pk.u[0] = f2bf(tile[i2][j]);
    pk.u[1] = f2bf(tile[i2 + 1][j]);
    *(unsigned int*)&d[(long)(tc + j) * R + tr + i2] = pk.w;
  }
}

// ---------------- routing ----------------

__global__ void init_kernel(int* counts, int* ptok, float* wslot) {
  int i = blockIdx.x * 256 + threadIdx.x;
  if (i < En) counts[i] = 0;
  if (i < CAP) { ptok[i] = 0; wslot[i] = 0.0f; }   // pad slots: token 0, weight 0
}

__global__ void router_kernel(const float* __restrict__ X, const float* __restrict__ GW,
                              const float* __restrict__ bias,
                              int* __restrict__ route_e, float* __restrict__ route_w,
                              int* __restrict__ counts) {
  int t = blockIdx.x, lane = threadIdx.x;
  const float* xr = X + (long)t * Dm;
  double acc[En];
#pragma unroll
  for (int e = 0; e < En; e++) acc[e] = 0.0;
  for (int d = lane; d < Dm; d += 64) {
    double xv = (double)xr[d];
#pragma unroll
    for (int e = 0; e < En; e++) acc[e] += xv * (double)GW[e * Dm + d];
  }
#pragma unroll
  for (int off = 32; off > 0; off >>= 1) {
#pragma unroll
    for (int e = 0; e < En; e++) acc[e] += __shfl_down(acc[e], off);
  }
  if (lane == 0) {
    double sc[En], sel[En];
#pragma unroll
    for (int e = 0; e < En; e++) {
      sc[e] = 1.0 / (1.0 + exp(-acc[e]));
      sel[e] = sc[e] + (double)bias[e];
    }
    int i0 = 0;
#pragma unroll
    for (int e = 1; e < En; e++) if (sel[e] > sel[i0]) i0 = e;
    int i1 = (i0 == 0) ? 1 : 0;
#pragma unroll
    for (int e = 0; e < En; e++) if (e != i0 && sel[e] > sel[i1]) i1 = e;
    double s = sc[i0] + sc[i1];
    if (s < 1e-12) s = 1e-12;
    route_e[t * 2] = i0;  route_e[t * 2 + 1] = i1;
    route_w[t * 2] = (float)(sc[i0] / s);  route_w[t * 2 + 1] = (float)(sc[i1] / s);
    atomicAdd(&counts[i0], 1);  atomicAdd(&counts[i1], 1);
  }
}

__global__ void offsets_kernel(const int* __restrict__ counts,
                               int* __restrict__ offs, int* __restrict__ fill) {
  if (threadIdx.x == 0) {
    int off = 0;
    for (int e = 0; e < En; e++) {
      offs[e] = off; fill[e] = off;
      off += (counts[e] + 255) & ~255;      // pad each expert segment to 256
    }
    offs[En] = off;
  }
}

__global__ void scatter_kernel(const int* __restrict__ re, const float* __restrict__ rw,
                               int* __restrict__ fill,
                               int* __restrict__ pt, float* __restrict__ wslot) {
  int i = blockIdx.x * 256 + threadIdx.x;
  if (i < Tn * 2) {
    int e = re[i];
    int slot = atomicAdd(&fill[e], 1);
    pt[slot] = i >> 1;
    wslot[slot] = rw[i];                    // routing weight lives with the slot
  }
}

// ---------------- 8-phase 256-row GEMM core ----------------
// BM=256, BK=64, 512 threads = 8 waves (2M x 4N), per-wave C 128x64.
// LDS (dynamic 128KB): [buf0: A 32K | B 32K][buf1: A 32K | B 32K]
// st_16x32 XOR swizzle via pre-swizzled global source (linear gload_lds dest).

DEV void mm16(floatx4 (&acc)[8][4], const short8 (&af)[4][2],
              const short8 (&bf)[4][2], int mq, int nq) {
#pragma unroll
  for (int i = 0; i < 4; i++)
#pragma unroll
    for (int n = 0; n < 2; n++)
#pragma unroll
      for (int kk = 0; kk < 2; kk++)
        acc[4 * mq + i][2 * nq + n] = __builtin_amdgcn_mfma_f32_16x16x32_bf16(
            af[i][kk], bf[2 * nq + n][kk], acc[4 * mq + i][2 * nq + n], 0, 0, 0);
}

// chunk c (c = j*512 + tid) lands at linear LDS byte c*16; swizzled layout:
// row = (c>>7)*16 + ((c>>2)&15), colb = ((c>>6)&1)*64 + (((c&3)<<4) ^ (c&32 ? 32 : 0))
DEV void chunk_rc(int c, int& rowh, int& colb) {
  rowh = ((c >> 7) << 4) | ((c >> 2) & 15);
  colb = (((c >> 6) & 1) << 6) | ((((c & 3) << 4)) ^ ((c & 32) ? 32 : 0));
}

DEV void gemm_core(char* LDS, const char* (&gA)[2][2], const char* (&gB)[2][2],
                   floatx4 (&acc)[8][4], int NT, int wm, int wn, int wv, int aswz) {
  const int bsel = (wn >> 1) * 16384 + ((wn & 1) << 13);
  const int wb = wv * 1024;
  unsigned base = ldsoff(LDS);
  unsigned aA0 = base + wm * 16384 + aswz;
  unsigned aB0 = base + 32768 + bsel + aswz;
  unsigned aA1 = aA0 + 65536, aB1 = aB0 + 65536;
  // prologue: tile0 complete (8 loads) + tile1 j0 rounds A,B (4 loads)
  stg(gB[0][0], LDS + 32768 + wb);
  stg(gB[1][0], LDS + 32768 + 16384 + wb);
  stg(gB[0][1], LDS + 32768 + 8192 + wb);
  stg(gB[1][1], LDS + 32768 + 16384 + 8192 + wb);
  stg(gA[0][0], LDS + wb);
  stg(gA[1][0], LDS + 16384 + wb);
  stg(gA[0][1], LDS + 8192 + wb);
  stg(gA[1][1], LDS + 16384 + 8192 + wb);
  stg(gA[0][0] + 128, LDS + 65536 + wb);
  stg(gA[1][0] + 128, LDS + 65536 + 16384 + wb);
  stg(gB[0][0] + 128, LDS + 65536 + 32768 + wb);
  stg(gB[1][0] + 128, LDS + 65536 + 32768 + 16384 + wb);
  VMC(4);
  BARR();
  short8 af[4][2], bf[4][2];

  auto tile = [&](int t, int b, unsigned aA, unsigned aB) {
    char* An = LDS + ((b ^ 1) << 16);
    char* Bn = An + 32768;
    char* Ac = LDS + (b << 16);
    char* Bc = Ac + 32768;
    const int kn = (t + 1) << 7, ka = (t + 2) << 7;
    const bool s1 = (t + 1 < NT), s2 = (t + 2 < NT);
    // ---- phase 0: quadrant (mq0,nq0); stage B(t+1) j1
    RDA_LO(af, aA); RDB_LO(bf, aB);
    if (s1) { stg(gB[0][1] + kn, Bn + 8192 + wb);
              stg(gB[1][1] + kn, Bn + 16384 + 8192 + wb); }
    LGKM8(); BARR(); LGKM0(); PRIO(1); mm16(acc, af, bf, 0, 0); PRIO(0); BARR();
    // ---- phase 1: (mq0,nq1); stage A(t+1) j1
    RDB_HI(bf, aB);
    if (s1) { stg(gA[0][1] + kn, An + 8192 + wb);
              stg(gA[1][1] + kn, An + 16384 + 8192 + wb); }
    BARR(); LGKM0(); PRIO(1); mm16(acc, af, bf, 0, 1); PRIO(0); BARR();
    // ---- phase 2: (mq1,nq0); A-j0 of current buf dead -> stage A(t+2) j0
    RDA_HI(af, aA);
    if (s2) { stg(gA[0][0] + ka, Ac + wb);
              stg(gA[1][0] + ka, Ac + 16384 + wb); }
    BARR(); LGKM0(); PRIO(1); mm16(acc, af, bf, 1, 0); PRIO(0); BARR();
    // ---- phase 3: (mq1,nq1); B-j0 of current buf dead -> stage B(t+2) j0
    if (s2) { stg(gB[0][0] + ka, Bc + wb);
              stg(gB[1][0] + ka, Bc + 16384 + wb); }
    BARR(); LGKM0(); PRIO(1); mm16(acc, af, bf, 1, 1); PRIO(0);
    if (s2)      { VMC(4); }   // all of t+1 landed; t+2 j0 stays in flight
    else if (s1) { VMC(0); }   // pipeline drain near the end
    BARR();
  };
#pragma unroll 1
  for (int t2 = 0; t2 < NT; t2 += 2) {
    tile(t2, 0, aA0, aB0);
    tile(t2 + 1, 1, aA1, aB1);
  }
}

// ---------------- stage 1 (h): routed and shared variants ----------------
// B tile interleaves W1/W3 in 32-row chunks; wave wn covers cols
// n0+wn*32..+31: acc[.][0..1]=h1 frags, acc[.][2..3]=h3 frags.

DEV void h_body(const unsigned short* Xb, const unsigned short* B1p,
                const unsigned short* B3p, unsigned short* ap, int Nact,
                int m0, int n0, const int* ptok, bool routed, char* LDS) {
  int tid = threadIdx.x, wv = tid >> 6, lane = tid & 63;
  int wm = wv >> 2, wn = wv & 3;
  int fr = lane & 15, fq = lane >> 4;
  int aswz = fr * 64 + ((fq * 16) ^ ((fr & 8) << 2));

  const char* gA[2][2]; const char* gB[2][2];
#pragma unroll
  for (int j = 0; j < 2; j++) {
    int rowh, colb;
    chunk_rc(j * 512 + tid, rowh, colb);
#pragma unroll
    for (int h = 0; h < 2; h++) {
      int grA = m0 + h * 128 + rowh;
      long ra = routed ? (long)ptok[grA] : (long)grA;
      gA[h][j] = (const char*)Xb + ra * (long)(Dm * 2) + colb;
      int rt = h * 128 + rowh;
      const unsigned short* src = ((rt >> 5) & 1) ? B3p : B1p;
      long rb = (long)n0 + ((rt >> 6) << 5) + (rt & 31);
      gB[h][j] = (const char*)src + rb * (long)(Dm * 2) + colb;
    }
  }
  floatx4 acc[8][4];
#pragma unroll
  for (int i = 0; i < 8; i++)
#pragma unroll
    for (int n = 0; n < 4; n++) acc[i][n] = (floatx4)0.0f;

  gemm_core(LDS, gA, gB, acc, Dm / 64, wm, wn, wv, aswz);

#pragma unroll
  for (int mi = 0; mi < 8; mi++)
#pragma unroll
    for (int n = 0; n < 2; n++)
#pragma unroll
      for (int r = 0; r < 4; r++) {
        int row = m0 + wm * 128 + mi * 16 + fq * 4 + r;
        int col = n0 + wn * 32 + n * 16 + fr;
        float h1 = acc[mi][n][r], h3 = acc[mi][n + 2][r];
        float v = h1 / (1.0f + __expf(-h1)) * h3;
        ap[(long)row * Nact + col] = f2bf(v);
      }
}

__global__ __launch_bounds__(512, 2)
void h_routed_k(const unsigned short* __restrict__ Xb,
                const unsigned short* __restrict__ W1t,
                const unsigned short* __restrict__ W3t,
                unsigned short* __restrict__ act,
                const int* __restrict__ ptok,
                const int* __restrict__ offs) {
  extern __shared__ char LDS[];
  int bid = xcd_swz(blockIdx.x, RT_H);
  int m0 = (bid % 40) * 256, n0 = (bid / 40) * 128;
  if (m0 >= offs[En]) return;
  int e = 0;
  while (!(m0 >= offs[e] && m0 < offs[e + 1])) e++;
  h_body(Xb, W1t + (long)e * In * Dm, W3t + (long)e * In * Dm,
         act, In, m0, n0, ptok, true, LDS);
}

__global__ __launch_bounds__(512, 2)
void h_shared_k(const unsigned short* __restrict__ Xb,
                const unsigned short* __restrict__ sw1b,
                const unsigned short* __restrict__ sw3b,
                unsigned short* __restrict__ actS) {
  extern __shared__ char LDS[];
  int bid = xcd_swz(blockIdx.x, SH_H);
  int m0 = (bid % 16) * 256, n0 = (bid / 16) * 128;
  h_body(Xb, sw1b, sw3b, actS, SIn, m0, n0, nullptr, false, LDS);
}

// ---------------- stage 2 (o): routed (atomic combine) and shared ----------------

DEV void o_core(const unsigned short* Apt, const unsigned short* Bpt,
                int lda, int ldb, int NT, int m0, int n0,
                floatx4 (&acc)[8][4], char* LDS) {
  int tid = threadIdx.x, wv = tid >> 6, lane = tid & 63;
  int wm = wv >> 2, wn = wv & 3;
  int fr = lane & 15, fq = lane >> 4;
  int aswz = fr * 64 + ((fq * 16) ^ ((fr & 8) << 2));

  const char* gA[2][2]; const char* gB[2][2];
#pragma unroll
  for (int j = 0; j < 2; j++) {
    int rowh, colb;
    chunk_rc(j * 512 + tid, rowh, colb);
#pragma unroll
    for (int h = 0; h < 2; h++) {
      gA[h][j] = (const char*)Apt + (long)(m0 + h * 128 + rowh) * (lda * 2) + colb;
      gB[h][j] = (const char*)Bpt + (long)(n0 + h * 128 + rowh) * (ldb * 2) + colb;
    }
  }
#pragma unroll
  for (int i = 0; i < 8; i++)
#pragma unroll
    for (int n = 0; n < 4; n++) acc[i][n] = (floatx4)0.0f;

  gemm_core(LDS, gA, gB, acc, NT, wm, wn, wv, aswz);
}

__global__ __launch_bounds__(512, 2)
void o_routed_k(const unsigned short* __restrict__ act,
                const unsigned short* __restrict__ W2t,
                float* __restrict__ out,
                const int* __restrict__ ptok,
                const float* __restrict__ wslot,
                const int* __restrict__ offs) {
  extern __shared__ char LDS[];
  int bid = xcd_swz(blockIdx.x, RT_O);
  int m0 = (bid % 40) * 256, n0 = (bid / 40) * 256;
  if (m0 >= offs[En]) return;
  int e = 0;
  while (!(m0 >= offs[e] && m0 < offs[e + 1])) e++;
  floatx4 acc[8][4];
  o_core(act, W2t + (long)e * Dm * In, In, In, In / 64, m0, n0, acc, LDS);

  int lane = threadIdx.x & 63, wv = threadIdx.x >> 6;
  int wm = wv >> 2, wn = wv & 3;
  int fr = lane & 15, fq = lane >> 4;
  // fused combine: out[tok] += w * y  (pad slots have w == 0)
#pragma unroll
  for (int mi = 0; mi < 8; mi++)
#pragma unroll
    for (int r = 0; r < 4; r++) {
      int row = m0 + wm * 128 + mi * 16 + fq * 4 + r;
      int tok = ptok[row];
      float w = wslot[row];
      if (w != 0.0f) {
#pragma unroll
        for (int ni = 0; ni < 4; ni++) {
          int col = n0 + wn * 64 + ni * 16 + fr;
          atomicAdd(&out[(long)tok * Dm + col], w * acc[mi][ni][r]);
        }
      }
    }
}

__global__ __launch_bounds__(512, 2)
void o_shared_k(const unsigned short* __restrict__ actS,
                const unsigned short* __restrict__ sw2b,
                float* __restrict__ out) {
  extern __shared__ char LDS[];
  int bid = xcd_swz(blockIdx.x, SH_O);
  int m0 = (bid % 16) * 256, n0 = (bid / 16) * 256;
  floatx4 acc[8][4];
  o_core(actS, sw2b, SIn, SIn, SIn / 64, m0, n0, acc, LDS);

  int lane = threadIdx.x & 63, wv = threadIdx.x >> 6;
  int wm = wv >> 2, wn = wv & 3;
  int fr = lane & 15, fq = lane >> 4;
#pragma unroll
  for (int mi = 0; mi < 8; mi++)
#pragma unroll
    for (int r = 0; r < 4; r++) {
      int row = m0 + wm * 128 + mi * 16 + fq * 4 + r;
#pragma unroll
      for (int ni = 0; ni < 4; ni++) {
        int col = n0 + wn * 64 + ni * 16 + fr;
        out[(long)row * Dm + col] = acc[mi][ni][r];
      }
    }
}

// ---------------- launch ----------------

extern "C" void kernel_launch(void* const* d_in, const int* in_sizes, int n_in,
                              void* d_out, int out_size, void* d_ws, size_t ws_size,
                              hipStream_t stream) {
  const float* x    = (const float*)d_in[0];
  const float* gw   = (const float*)d_in[1];
  const float* bias = (const float*)d_in[2];
  const float* W1   = (const float*)d_in[3];
  const float* W3   = (const float*)d_in[4];
  const float* W2   = (const float*)d_in[5];
  const float* sw1  = (const float*)d_in[6];
  const float* sw3  = (const float*)d_in[7];
  const float* sw2  = (const float*)d_in[8];
  float* out = (float*)d_out;

  static bool attr_done = false;
  if (!attr_done) {
    hipFuncSetAttribute(reinterpret_cast<const void*>(h_routed_k),
                        hipFuncAttributeMaxDynamicSharedMemorySize, 131072);
    hipFuncSetAttribute(reinterpret_cast<const void*>(h_shared_k),
                        hipFuncAttributeMaxDynamicSharedMemorySize, 131072);
    hipFuncSetAttribute(reinterpret_cast<const void*>(o_routed_k),
                        hipFuncAttributeMaxDynamicSharedMemorySize, 131072);
    hipFuncSetAttribute(reinterpret_cast<const void*>(o_shared_k),
                        hipFuncAttributeMaxDynamicSharedMemorySize, 131072);
    attr_done = true;
  }

  char* p = (char*)d_ws;
  auto alloc = [&](size_t bytes) {
    char* r = p; p += (bytes + 255) & ~(size_t)255; return r;
  };
  unsigned short* Xb   = (unsigned short*)alloc((size_t)Tn * Dm * 2);
  unsigned short* W1t  = (unsigned short*)alloc((size_t)En * In * Dm * 2);
  unsigned short* W3t  = (unsigned short*)alloc((size_t)En * In * Dm * 2);
  unsigned short* W2t  = (unsigned short*)alloc((size_t)En * Dm * In * 2);
  unsigned short* sw1b = (unsigned short*)alloc((size_t)SIn * Dm * 2);
  unsigned short* sw3b = (unsigned short*)alloc((size_t)SIn * Dm * 2);
  unsigned short* sw2b = (unsigned short*)alloc((size_t)Dm * SIn * 2);
  unsigned short* act  = (unsigned short*)alloc((size_t)CAP * In * 2);
  unsigned short* actS = (unsigned short*)alloc((size_t)Tn * SIn * 2);
  int*   route_e = (int*)alloc(Tn * 2 * 4);
  float* route_w = (float*)alloc(Tn * 2 * 4);
  int*   counts  = (int*)alloc(256);
  int*   offs    = (int*)alloc(256);
  int*   fill    = (int*)alloc(256);
  int*   ptok    = (int*)alloc(CAP * 4);
  float* wslot   = (float*)alloc(CAP * 4);

  // conversions (inputs restored before every call -> must reconvert every call)
  convert_all_kernel<<<dim3(Tn * Dm / 4 / 256, 4), 256, 0, stream>>>(
      x, sw1, sw3, sw2, Xb, sw1b, sw3b, sw2b);
  transpose_all_kernel<<<dim3((Dm / 64) * (In / 64), En, 3), 256, 0, stream>>>(
      W1, W3, W2, W1t, W3t, W2t);

  // routing
  init_kernel<<<(CAP + 255) / 256, 256, 0, stream>>>(counts, ptok, wslot);
  router_kernel<<<Tn, 64, 0, stream>>>(x, gw, bias, route_e, route_w, counts);
  offsets_kernel<<<1, 1, 0, stream>>>(counts, offs, fill);
  scatter_kernel<<<Tn * 2 / 256, 256, 0, stream>>>(route_e, route_w, fill, ptok, wslot);

  // GEMM stages (128KB dynamic LDS each), split for per-kernel visibility
  h_shared_k<<<SH_H, 512, 131072, stream>>>(Xb, sw1b, sw3b, actS);
  h_routed_k<<<RT_H, 512, 131072, stream>>>(Xb, W1t, W3t, act, ptok, offs);
  o_shared_k<<<SH_O, 512, 131072, stream>>>(actS, sw2b, out);
  o_routed_k<<<RT_O, 512, 131072, stream>>>(act, W2t, out, ptok, wslot, offs);
}

// Round 4
// 832.471 us; speedup vs baseline: 1.1000x; 1.1000x over previous
//
#include <hip/hip_runtime.h>

#define DEV __device__ __forceinline__

typedef __attribute__((ext_vector_type(8))) short short8;
typedef __attribute__((ext_vector_type(4))) float floatx4;

constexpr int Tn  = 4096;   // tokens (B*S)
constexpr int Dm  = 2048;   // model dim
constexpr int In  = 1408;   // expert inter dim
constexpr int En  = 8;      // experts
constexpr int SIn = 2816;   // shared inter dim (2*1408)
constexpr int CAP = 10240;  // 8192 pairs + 8*256 padding (segments padded to 256)

constexpr int SH_H = (Tn / 256) * (SIn / 128);    // 16*22 = 352 shared h tiles
constexpr int SH_O = (Tn / 256) * (Dm / 256);     // 16*8  = 128 shared o tiles
constexpr int NBLK = 256;                         // persistent blocks = CUs

DEV unsigned short f2bf(float f) {          // fp32 -> bf16 RNE
  unsigned int u = __float_as_uint(f);
  u += 0x7FFF + ((u >> 16) & 1);
  return (unsigned short)(u >> 16);
}

DEV float bf2f(unsigned short u) {
  return __uint_as_float(((unsigned int)u) << 16);
}

DEV void stg(const char* g, char* l) {
  // async global->LDS, 16B/lane; LDS dst = wave-uniform base + lane*16
  __builtin_amdgcn_global_load_lds(
      (const __attribute__((address_space(1))) unsigned int*)g,
      (__attribute__((address_space(3))) unsigned int*)l, 16, 0, 0);
}

DEV unsigned ldsoff(const void* p) {        // generic LDS ptr -> 32-bit LDS byte offset
  return (unsigned)(unsigned long long)(__attribute__((address_space(3))) const char*)p;
}

#define BARR()  __builtin_amdgcn_s_barrier()
#define LGKM0() do { asm volatile("s_waitcnt lgkmcnt(0)" ::: "memory"); \
                     __builtin_amdgcn_sched_barrier(0); } while (0)
#define LGKM8() asm volatile("s_waitcnt lgkmcnt(8)" ::: "memory")
#define VMC(n)  asm volatile("s_waitcnt vmcnt(" #n ")" ::: "memory")
#define PRIO(x) __builtin_amdgcn_s_setprio(x)

// inline-asm ds_read_b128 (immediate offsets; ordering via LGKM/VMC + barriers)
#define DSR(dst, addr, OFFSTR) \
  asm volatile("ds_read_b128 %0, %1 offset:" OFFSTR : "=v"(dst) : "v"(addr))

#define RDA_LO(af, a) do { \
  DSR(af[0][0], a, "0");     DSR(af[0][1], a, "1024"); \
  DSR(af[1][0], a, "2048");  DSR(af[1][1], a, "3072"); \
  DSR(af[2][0], a, "4096");  DSR(af[2][1], a, "5120"); \
  DSR(af[3][0], a, "6144");  DSR(af[3][1], a, "7168"); } while (0)
#define RDA_HI(af, a) do { \
  DSR(af[0][0], a, "8192");  DSR(af[0][1], a, "9216"); \
  DSR(af[1][0], a, "10240"); DSR(af[1][1], a, "11264"); \
  DSR(af[2][0], a, "12288"); DSR(af[2][1], a, "13312"); \
  DSR(af[3][0], a, "14336"); DSR(af[3][1], a, "15360"); } while (0)
#define RDB_LO(bf, a) do { \
  DSR(bf[0][0], a, "0");    DSR(bf[0][1], a, "1024"); \
  DSR(bf[1][0], a, "2048"); DSR(bf[1][1], a, "3072"); } while (0)
#define RDB_HI(bf, a) do { \
  DSR(bf[2][0], a, "4096"); DSR(bf[2][1], a, "5120"); \
  DSR(bf[3][0], a, "6144"); DSR(bf[3][1], a, "7168"); } while (0)

// ---------------- merged conversion kernels ----------------

__global__ void convert_all_kernel(const float* __restrict__ x,
                                   const float* __restrict__ sw1,
                                   const float* __restrict__ sw3,
                                   const float* __restrict__ sw2,
                                   unsigned short* __restrict__ Xb,
                                   unsigned short* __restrict__ sw1b,
                                   unsigned short* __restrict__ sw3b,
                                   unsigned short* __restrict__ sw2b) {
  int y = blockIdx.y;
  const float* src; unsigned short* dst; int n4;
  if (y == 0)      { src = x;   dst = Xb;   n4 = Tn * Dm / 4; }
  else if (y == 1) { src = sw1; dst = sw1b; n4 = SIn * Dm / 4; }
  else if (y == 2) { src = sw3; dst = sw3b; n4 = SIn * Dm / 4; }
  else             { src = sw2; dst = sw2b; n4 = Dm * SIn / 4; }
  int i = blockIdx.x * 256 + threadIdx.x;
  if (i >= n4) return;
  float4 v = ((const float4*)src)[i];
  union { unsigned short u[4]; unsigned long long ll; } p;
  p.u[0] = f2bf(v.x); p.u[1] = f2bf(v.y); p.u[2] = f2bf(v.z); p.u[3] = f2bf(v.w);
  *(unsigned long long*)(dst + (long)i * 4) = p.ll;
}

// 64x64-tile transpose+convert: float4 reads, ushort2 packed writes
__global__ void transpose_all_kernel(const float* __restrict__ W1,
                                     const float* __restrict__ W3,
                                     const float* __restrict__ W2,
                                     unsigned short* __restrict__ W1t,
                                     unsigned short* __restrict__ W3t,
                                     unsigned short* __restrict__ W2t) {
  __shared__ float tile[64][65];
  int z = blockIdx.z;
  const float* s0; unsigned short* d0; int R, C;
  if (z == 0)      { s0 = W1; d0 = W1t; R = Dm; C = In; }
  else if (z == 1) { s0 = W3; d0 = W3t; R = Dm; C = In; }
  else             { s0 = W2; d0 = W2t; R = In; C = Dm; }
  int tilesC = C >> 6;
  int tr = (blockIdx.x / tilesC) << 6;
  int tc = (blockIdx.x % tilesC) << 6;
  const float* s = s0 + (long)blockIdx.y * R * C;
  unsigned short* d = d0 + (long)blockIdx.y * R * C;
  int rr = threadIdx.x >> 4, c4 = (threadIdx.x & 15) << 2;   // 16 rows x 16 float4
#pragma unroll
  for (int p = 0; p < 4; p++) {
    float4 v = *(const float4*)&s[(long)(tr + rr + 16 * p) * C + tc + c4];
    tile[rr + 16 * p][c4]     = v.x;
    tile[rr + 16 * p][c4 + 1] = v.y;
    tile[rr + 16 * p][c4 + 2] = v.z;
    tile[rr + 16 * p][c4 + 3] = v.w;
  }
  __syncthreads();
  int oc = threadIdx.x >> 5, i2 = (threadIdx.x & 31) << 1;   // 8 out-rows x 32 pairs
#pragma unroll
  for (int p = 0; p < 8; p++) {
    int j = oc + 8 * p;
    union { unsigned short u[2]; unsigned int w; } pk;
    pk.u[0] = f2bf(tile[i2][j]);
    pk.u[1] = f2bf(tile[i2 + 1][j]);
    *(unsigned int*)&d[(long)(tc + j) * R + tr + i2] = pk.w;
  }
}

// ---------------- routing ----------------

__global__ void init_kernel(int* counts, int* ptok) {
  int i = blockIdx.x * 256 + threadIdx.x;
  if (i < En) counts[i] = 0;
  if (i < CAP) ptok[i] = 0;                 // pads gather token 0 (harmless)
}

__global__ void router_kernel(const float* __restrict__ X, const float* __restrict__ GW,
                              const float* __restrict__ bias,
                              int* __restrict__ route_e, float* __restrict__ route_w,
                              int* __restrict__ counts) {
  int t = blockIdx.x, lane = threadIdx.x;
  const float* xr = X + (long)t * Dm;
  double acc[En];
#pragma unroll
  for (int e = 0; e < En; e++) acc[e] = 0.0;
  for (int d = lane; d < Dm; d += 64) {
    double xv = (double)xr[d];
#pragma unroll
    for (int e = 0; e < En; e++) acc[e] += xv * (double)GW[e * Dm + d];
  }
#pragma unroll
  for (int off = 32; off > 0; off >>= 1) {
#pragma unroll
    for (int e = 0; e < En; e++) acc[e] += __shfl_down(acc[e], off);
  }
  if (lane == 0) {
    double sc[En], sel[En];
#pragma unroll
    for (int e = 0; e < En; e++) {
      sc[e] = 1.0 / (1.0 + exp(-acc[e]));
      sel[e] = sc[e] + (double)bias[e];
    }
    int i0 = 0;
#pragma unroll
    for (int e = 1; e < En; e++) if (sel[e] > sel[i0]) i0 = e;
    int i1 = (i0 == 0) ? 1 : 0;
#pragma unroll
    for (int e = 0; e < En; e++) if (e != i0 && sel[e] > sel[i1]) i1 = e;
    double s = sc[i0] + sc[i1];
    if (s < 1e-12) s = 1e-12;
    route_e[t * 2] = i0;  route_e[t * 2 + 1] = i1;
    route_w[t * 2] = (float)(sc[i0] / s);  route_w[t * 2 + 1] = (float)(sc[i1] / s);
    atomicAdd(&counts[i0], 1);  atomicAdd(&counts[i1], 1);
  }
}

__global__ void offsets_kernel(const int* __restrict__ counts,
                               int* __restrict__ offs, int* __restrict__ fill) {
  if (threadIdx.x == 0) {
    int off = 0;
    for (int e = 0; e < En; e++) {
      offs[e] = off; fill[e] = off;
      off += (counts[e] + 255) & ~255;      // pad each expert segment to 256
    }
    offs[En] = off;
  }
}

__global__ void scatter_kernel(const int* __restrict__ re, int* __restrict__ fill,
                               int* __restrict__ pt, int* __restrict__ pslot) {
  int i = blockIdx.x * 256 + threadIdx.x;
  if (i < Tn * 2) {
    int e = re[i];
    int slot = atomicAdd(&fill[e], 1);
    pt[slot] = i >> 1;
    pslot[i] = slot;                        // inverse map pair -> slot
  }
}

// ---------------- 8-phase 256-row GEMM core ----------------
// BM=256, BK=64, 512 threads = 8 waves (2M x 4N), per-wave C 128x64.
// LDS (dynamic 128KB): [buf0: A 32K | B 32K][buf1: A 32K | B 32K]
// st_16x32 XOR swizzle via pre-swizzled global source (linear gload_lds dest).

DEV void mm16(floatx4 (&acc)[8][4], const short8 (&af)[4][2],
              const short8 (&bf)[4][2], int mq, int nq) {
#pragma unroll
  for (int i = 0; i < 4; i++)
#pragma unroll
    for (int n = 0; n < 2; n++)
#pragma unroll
      for (int kk = 0; kk < 2; kk++)
        acc[4 * mq + i][2 * nq + n] = __builtin_amdgcn_mfma_f32_16x16x32_bf16(
            af[i][kk], bf[2 * nq + n][kk], acc[4 * mq + i][2 * nq + n], 0, 0, 0);
}

// chunk c (c = j*512 + tid) lands at linear LDS byte c*16; swizzled layout:
// row = (c>>7)*16 + ((c>>2)&15), colb = ((c>>6)&1)*64 + (((c&3)<<4) ^ (c&32 ? 32 : 0))
DEV void chunk_rc(int c, int& rowh, int& colb) {
  rowh = ((c >> 7) << 4) | ((c >> 2) & 15);
  colb = (((c >> 6) & 1) << 6) | ((((c & 3) << 4)) ^ ((c & 32) ? 32 : 0));
}

DEV void gemm_core(char* LDS, const char* (&gA)[2][2], const char* (&gB)[2][2],
                   floatx4 (&acc)[8][4], int NT, int wm, int wn, int wv, int aswz) {
  const int bsel = (wn >> 1) * 16384 + ((wn & 1) << 13);
  const int wb = wv * 1024;
  unsigned base = ldsoff(LDS);
  unsigned aA0 = base + wm * 16384 + aswz;
  unsigned aB0 = base + 32768 + bsel + aswz;
  unsigned aA1 = aA0 + 65536, aB1 = aB0 + 65536;
  // prologue: tile0 complete (8 loads) + tile1 j0 rounds A,B (4 loads)
  stg(gB[0][0], LDS + 32768 + wb);
  stg(gB[1][0], LDS + 32768 + 16384 + wb);
  stg(gB[0][1], LDS + 32768 + 8192 + wb);
  stg(gB[1][1], LDS + 32768 + 16384 + 8192 + wb);
  stg(gA[0][0], LDS + wb);
  stg(gA[1][0], LDS + 16384 + wb);
  stg(gA[0][1], LDS + 8192 + wb);
  stg(gA[1][1], LDS + 16384 + 8192 + wb);
  stg(gA[0][0] + 128, LDS + 65536 + wb);
  stg(gA[1][0] + 128, LDS + 65536 + 16384 + wb);
  stg(gB[0][0] + 128, LDS + 65536 + 32768 + wb);
  stg(gB[1][0] + 128, LDS + 65536 + 32768 + 16384 + wb);
  VMC(4);
  BARR();
  short8 af[4][2], bf[4][2];

  auto tile = [&](int t, int b, unsigned aA, unsigned aB) {
    char* An = LDS + ((b ^ 1) << 16);
    char* Bn = An + 32768;
    char* Ac = LDS + (b << 16);
    char* Bc = Ac + 32768;
    const int kn = (t + 1) << 7, ka = (t + 2) << 7;
    const bool s1 = (t + 1 < NT), s2 = (t + 2 < NT);
    // ---- phase 0: quadrant (mq0,nq0); stage B(t+1) j1
    RDA_LO(af, aA); RDB_LO(bf, aB);
    if (s1) { stg(gB[0][1] + kn, Bn + 8192 + wb);
              stg(gB[1][1] + kn, Bn + 16384 + 8192 + wb); }
    LGKM8(); BARR(); LGKM0(); PRIO(1); mm16(acc, af, bf, 0, 0); PRIO(0); BARR();
    // ---- phase 1: (mq0,nq1); stage A(t+1) j1
    RDB_HI(bf, aB);
    if (s1) { stg(gA[0][1] + kn, An + 8192 + wb);
              stg(gA[1][1] + kn, An + 16384 + 8192 + wb); }
    BARR(); LGKM0(); PRIO(1); mm16(acc, af, bf, 0, 1); PRIO(0); BARR();
    // ---- phase 2: (mq1,nq0); A-j0 of current buf dead -> stage A(t+2) j0
    RDA_HI(af, aA);
    if (s2) { stg(gA[0][0] + ka, Ac + wb);
              stg(gA[1][0] + ka, Ac + 16384 + wb); }
    BARR(); LGKM0(); PRIO(1); mm16(acc, af, bf, 1, 0); PRIO(0); BARR();
    // ---- phase 3: (mq1,nq1); B-j0 of current buf dead -> stage B(t+2) j0
    if (s2) { stg(gB[0][0] + ka, Bc + wb);
              stg(gB[1][0] + ka, Bc + 16384 + wb); }
    BARR(); LGKM0(); PRIO(1); mm16(acc, af, bf, 1, 1); PRIO(0);
    if (s2)      { VMC(4); }   // all of t+1 landed; t+2 j0 stays in flight
    else if (s1) { VMC(0); }   // pipeline drain near the end
    BARR();
  };
#pragma unroll 1
  for (int t2 = 0; t2 < NT; t2 += 2) {
    tile(t2, 0, aA0, aB0);
    tile(t2 + 1, 1, aA1, aB1);
  }
}

// ---------------- stage 1 (h): persistent merged kernel ----------------
// B tile interleaves W1/W3 in 32-row chunks; wave wn covers cols
// n0+wn*32..+31: acc[.][0..1]=h1 frags, acc[.][2..3]=h3 frags.

DEV void h_body(const unsigned short* Xb, const unsigned short* B1p,
                const unsigned short* B3p, unsigned short* ap, int Nact,
                int m0, int n0, const int* ptok, bool routed, char* LDS) {
  int tid = threadIdx.x, wv = tid >> 6, lane = tid & 63;
  int wm = wv >> 2, wn = wv & 3;
  int fr = lane & 15, fq = lane >> 4;
  int aswz = fr * 64 + ((fq * 16) ^ ((fr & 8) << 2));

  const char* gA[2][2]; const char* gB[2][2];
#pragma unroll
  for (int j = 0; j < 2; j++) {
    int rowh, colb;
    chunk_rc(j * 512 + tid, rowh, colb);
#pragma unroll
    for (int h = 0; h < 2; h++) {
      int grA = m0 + h * 128 + rowh;
      long ra = routed ? (long)ptok[grA] : (long)grA;
      gA[h][j] = (const char*)Xb + ra * (long)(Dm * 2) + colb;
      int rt = h * 128 + rowh;
      const unsigned short* src = ((rt >> 5) & 1) ? B3p : B1p;
      long rb = (long)n0 + ((rt >> 6) << 5) + (rt & 31);
      gB[h][j] = (const char*)src + rb * (long)(Dm * 2) + colb;
    }
  }
  floatx4 acc[8][4];
#pragma unroll
  for (int i = 0; i < 8; i++)
#pragma unroll
    for (int n = 0; n < 4; n++) acc[i][n] = (floatx4)0.0f;

  gemm_core(LDS, gA, gB, acc, Dm / 64, wm, wn, wv, aswz);

#pragma unroll
  for (int mi = 0; mi < 8; mi++)
#pragma unroll
    for (int n = 0; n < 2; n++)
#pragma unroll
      for (int r = 0; r < 4; r++) {
        int row = m0 + wm * 128 + mi * 16 + fq * 4 + r;
        int col = n0 + wn * 32 + n * 16 + fr;
        float h1 = acc[mi][n][r], h3 = acc[mi][n + 2][r];
        float v = h1 / (1.0f + __expf(-h1)) * h3;
        ap[(long)row * Nact + col] = f2bf(v);
      }
}

__global__ __launch_bounds__(512, 1)
void h_all(const unsigned short* __restrict__ Xb,
           const unsigned short* __restrict__ W1t,
           const unsigned short* __restrict__ W3t,
           const unsigned short* __restrict__ sw1b,
           const unsigned short* __restrict__ sw3b,
           unsigned short* __restrict__ act,
           unsigned short* __restrict__ actS,
           const int* __restrict__ ptok,
           const int* __restrict__ offs) {
  extern __shared__ char LDS[];
  const int Mr = offs[En] >> 8;             // live routed m-tiles (total padded to 256)
  const int RT = Mr * (In / 128);           // live routed tiles (no empties)
  const int TT = RT + SH_H;
#pragma unroll 1
  for (int t = blockIdx.x; t < TT; t += NBLK) {
    if (t < RT) {
      int m0 = (t % Mr) * 256, n0 = (t / Mr) * 128;
      int e = 0;
      while (!(m0 >= offs[e] && m0 < offs[e + 1])) e++;
      h_body(Xb, W1t + (long)e * In * Dm, W3t + (long)e * In * Dm,
             act, In, m0, n0, ptok, true, LDS);
    } else {
      int u = t - RT;
      int m0 = (u & 15) * 256, n0 = (u >> 4) * 128;
      h_body(Xb, sw1b, sw3b, actS, SIn, m0, n0, nullptr, false, LDS);
    }
  }
}

// ---------------- stage 2 (o): persistent merged kernel ----------------

DEV void o_core(const unsigned short* Apt, const unsigned short* Bpt,
                int lda, int ldb, int NT, int m0, int n0,
                floatx4 (&acc)[8][4], char* LDS) {
  int tid = threadIdx.x, wv = tid >> 6, lane = tid & 63;
  int wm = wv >> 2, wn = wv & 3;
  int fr = lane & 15, fq = lane >> 4;
  int aswz = fr * 64 + ((fq * 16) ^ ((fr & 8) << 2));

  const char* gA[2][2]; const char* gB[2][2];
#pragma unroll
  for (int j = 0; j < 2; j++) {
    int rowh, colb;
    chunk_rc(j * 512 + tid, rowh, colb);
#pragma unroll
    for (int h = 0; h < 2; h++) {
      gA[h][j] = (const char*)Apt + (long)(m0 + h * 128 + rowh) * (lda * 2) + colb;
      gB[h][j] = (const char*)Bpt + (long)(n0 + h * 128 + rowh) * (ldb * 2) + colb;
    }
  }
#pragma unroll
  for (int i = 0; i < 8; i++)
#pragma unroll
    for (int n = 0; n < 4; n++) acc[i][n] = (floatx4)0.0f;

  gemm_core(LDS, gA, gB, acc, NT, wm, wn, wv, aswz);
}

__global__ __launch_bounds__(512, 1)
void o_all(const unsigned short* __restrict__ act,
           const unsigned short* __restrict__ actS,
           const unsigned short* __restrict__ W2t,
           const unsigned short* __restrict__ sw2b,
           unsigned short* __restrict__ yR,
           float* __restrict__ out,
           const int* __restrict__ offs) {
  extern __shared__ char LDS[];
  const int Mr = offs[En] >> 8;
  const int RT = Mr * (Dm / 256);           // live routed o tiles
  const int TT = RT + SH_O;
  int lane = threadIdx.x & 63, wv = threadIdx.x >> 6;
  int wm = wv >> 2, wn = wv & 3;
  int fr = lane & 15, fq = lane >> 4;
#pragma unroll 1
  for (int t = blockIdx.x; t < TT; t += NBLK) {
    floatx4 acc[8][4];
    if (t < RT) {
      int m0 = (t % Mr) * 256, n0 = (t / Mr) * 256;
      int e = 0;
      while (!(m0 >= offs[e] && m0 < offs[e + 1])) e++;
      o_core(act, W2t + (long)e * Dm * In, In, In, In / 64, m0, n0, acc, LDS);
#pragma unroll
      for (int mi = 0; mi < 8; mi++)
#pragma unroll
        for (int r = 0; r < 4; r++) {
          int row = m0 + wm * 128 + mi * 16 + fq * 4 + r;
#pragma unroll
          for (int ni = 0; ni < 4; ni++) {
            int col = n0 + wn * 64 + ni * 16 + fr;
            yR[(long)row * Dm + col] = f2bf(acc[mi][ni][r]);
          }
        }
    } else {
      int u = t - RT;
      int m0 = (u & 15) * 256, n0 = (u >> 4) * 256;
      o_core(actS, sw2b, SIn, SIn, SIn / 64, m0, n0, acc, LDS);
#pragma unroll
      for (int mi = 0; mi < 8; mi++)
#pragma unroll
        for (int r = 0; r < 4; r++) {
          int row = m0 + wm * 128 + mi * 16 + fq * 4 + r;
#pragma unroll
          for (int ni = 0; ni < 4; ni++) {
            int col = n0 + wn * 64 + ni * 16 + fr;
            out[(long)row * Dm + col] = acc[mi][ni][r];
          }
        }
    }
  }
}

// ---------------- combine: out[t] += w0*yR[s0] + w1*yR[s1] ----------------

__global__ void combine_kernel(const unsigned short* __restrict__ yR,
                               const int* __restrict__ pslot,
                               const float* __restrict__ rw,
                               float* __restrict__ out) {
  int idx = blockIdx.x * 256 + threadIdx.x;   // Tn * (Dm/4) threads
  int t = idx >> 9, c4 = idx & 511;           // Dm/4 = 512
  int s0 = pslot[t * 2], s1 = pslot[t * 2 + 1];
  float w0 = rw[t * 2], w1 = rw[t * 2 + 1];
  ushort4 a = ((const ushort4*)(yR + (long)s0 * Dm))[c4];
  ushort4 b = ((const ushort4*)(yR + (long)s1 * Dm))[c4];
  float4* op = (float4*)(out + (long)t * Dm) + c4;
  float4 o = *op;
  o.x += w0 * bf2f(a.x) + w1 * bf2f(b.x);
  o.y += w0 * bf2f(a.y) + w1 * bf2f(b.y);
  o.z += w0 * bf2f(a.z) + w1 * bf2f(b.z);
  o.w += w0 * bf2f(a.w) + w1 * bf2f(b.w);
  *op = o;
}

// ---------------- launch ----------------

extern "C" void kernel_launch(void* const* d_in, const int* in_sizes, int n_in,
                              void* d_out, int out_size, void* d_ws, size_t ws_size,
                              hipStream_t stream) {
  const float* x    = (const float*)d_in[0];
  const float* gw   = (const float*)d_in[1];
  const float* bias = (const float*)d_in[2];
  const float* W1   = (const float*)d_in[3];
  const float* W3   = (const float*)d_in[4];
  const float* W2   = (const float*)d_in[5];
  const float* sw1  = (const float*)d_in[6];
  const float* sw3  = (const float*)d_in[7];
  const float* sw2  = (const float*)d_in[8];
  float* out = (float*)d_out;

  static bool attr_done = false;
  if (!attr_done) {
    hipFuncSetAttribute(reinterpret_cast<const void*>(h_all),
                        hipFuncAttributeMaxDynamicSharedMemorySize, 131072);
    hipFuncSetAttribute(reinterpret_cast<const void*>(o_all),
                        hipFuncAttributeMaxDynamicSharedMemorySize, 131072);
    attr_done = true;
  }

  char* p = (char*)d_ws;
  auto alloc = [&](size_t bytes) {
    char* r = p; p += (bytes + 255) & ~(size_t)255; return r;
  };
  unsigned short* Xb   = (unsigned short*)alloc((size_t)Tn * Dm * 2);
  unsigned short* W1t  = (unsigned short*)alloc((size_t)En * In * Dm * 2);
  unsigned short* W3t  = (unsigned short*)alloc((size_t)En * In * Dm * 2);
  unsigned short* W2t  = (unsigned short*)alloc((size_t)En * Dm * In * 2);
  unsigned short* sw1b = (unsigned short*)alloc((size_t)SIn * Dm * 2);
  unsigned short* sw3b = (unsigned short*)alloc((size_t)SIn * Dm * 2);
  unsigned short* sw2b = (unsigned short*)alloc((size_t)Dm * SIn * 2);
  unsigned short* act  = (unsigned short*)alloc((size_t)CAP * In * 2);
  unsigned short* actS = (unsigned short*)alloc((size_t)Tn * SIn * 2);
  unsigned short* yR   = (unsigned short*)alloc((size_t)CAP * Dm * 2);
  int*   route_e = (int*)alloc(Tn * 2 * 4);
  float* route_w = (float*)alloc(Tn * 2 * 4);
  int*   counts  = (int*)alloc(256);
  int*   offs    = (int*)alloc(256);
  int*   fill    = (int*)alloc(256);
  int*   ptok    = (int*)alloc(CAP * 4);
  int*   pslot   = (int*)alloc(Tn * 2 * 4);

  // conversions (inputs restored before every call -> must reconvert every call)
  convert_all_kernel<<<dim3(Tn * Dm / 4 / 256, 4), 256, 0, stream>>>(
      x, sw1, sw3, sw2, Xb, sw1b, sw3b, sw2b);
  transpose_all_kernel<<<dim3((Dm / 64) * (In / 64), En, 3), 256, 0, stream>>>(
      W1, W3, W2, W1t, W3t, W2t);

  // routing
  init_kernel<<<(CAP + 255) / 256, 256, 0, stream>>>(counts, ptok);
  router_kernel<<<Tn, 64, 0, stream>>>(x, gw, bias, route_e, route_w, counts);
  offsets_kernel<<<1, 1, 0, stream>>>(counts, offs, fill);
  scatter_kernel<<<Tn * 2 / 256, 256, 0, stream>>>(route_e, fill, ptok, pslot);

  // persistent GEMM stages (256 blocks = 1/CU, 128KB dynamic LDS each)
  h_all<<<NBLK, 512, 131072, stream>>>(Xb, W1t, W3t, sw1b, sw3b, act, actS, ptok, offs);
  o_all<<<NBLK, 512, 131072, stream>>>(act, actS, W2t, sw2b, yR, out, offs);
  combine_kernel<<<Tn * (Dm / 4) / 256, 256, 0, stream>>>(yR, pslot, route_w, out);
}

// Round 5
// 703.906 us; speedup vs baseline: 1.3009x; 1.1826x over previous
//
#include <hip/hip_runtime.h>

#define DEV __device__ __forceinline__

typedef __attribute__((ext_vector_type(8))) short short8;
typedef __attribute__((ext_vector_type(4))) float floatx4;

constexpr int Tn  = 4096;   // tokens (B*S)
constexpr int Dm  = 2048;   // model dim
constexpr int In  = 1408;   // expert inter dim
constexpr int En  = 8;      // experts
constexpr int SIn = 2816;   // shared inter dim (2*1408)
constexpr int CAP = 10240;  // 8192 pairs + 8*256 padding (segments padded to 256)

constexpr int SH_H = (Tn / 256) * (SIn / 128);    // 16*22 = 352 shared h tiles
constexpr int SH_O = (Tn / 256) * (Dm / 256);     // 16*8  = 128 shared o tiles
constexpr int NBLK = 256;                         // persistent blocks = CUs

// prep kernel block ranges
constexpr int RB  = Tn / 4;                       // 1024 router blocks (4 tok each)
constexpr int IB  = CAP / 256;                    // 40 init blocks
constexpr int CXB = Tn * Dm / 4 / 256;            // 8192 convert-x blocks
constexpr int CWB = SIn * Dm / 4 / 256;           // 5632 per shared-weight convert
constexpr int TBZ = (Dm / 64) * (In / 64);        // 704 transpose tiles per (z,y)
constexpr int O1 = RB;                            // init
constexpr int O2 = O1 + IB;                       // conv x
constexpr int O3 = O2 + CXB;                      // conv sw1
constexpr int O4 = O3 + CWB;                      // conv sw3
constexpr int O5 = O4 + CWB;                      // conv sw2
constexpr int O6 = O5 + CWB;                      // transpose
constexpr int PREP_B = O6 + TBZ * En * 3;

DEV unsigned short f2bf(float f) {          // fp32 -> bf16 RNE
  unsigned int u = __float_as_uint(f);
  u += 0x7FFF + ((u >> 16) & 1);
  return (unsigned short)(u >> 16);
}

DEV float bf2f(unsigned short u) {
  return __uint_as_float(((unsigned int)u) << 16);
}

DEV void stg(const char* g, char* l) {
  // async global->LDS, 16B/lane; LDS dst = wave-uniform base + lane*16
  __builtin_amdgcn_global_load_lds(
      (const __attribute__((address_space(1))) unsigned int*)g,
      (__attribute__((address_space(3))) unsigned int*)l, 16, 0, 0);
}

DEV unsigned ldsoff(const void* p) {        // generic LDS ptr -> 32-bit LDS byte offset
  return (unsigned)(unsigned long long)(__attribute__((address_space(3))) const char*)p;
}

#define BARR()  __builtin_amdgcn_s_barrier()
#define LGKM0() do { asm volatile("s_waitcnt lgkmcnt(0)" ::: "memory"); \
                     __builtin_amdgcn_sched_barrier(0); } while (0)
#define LGKM8() asm volatile("s_waitcnt lgkmcnt(8)" ::: "memory")
#define VMC(n)  asm volatile("s_waitcnt vmcnt(" #n ")" ::: "memory")
#define PRIO(x) __builtin_amdgcn_s_setprio(x)

// inline-asm ds_read_b128 (immediate offsets; ordering via LGKM/VMC + barriers)
#define DSR(dst, addr, OFFSTR) \
  asm volatile("ds_read_b128 %0, %1 offset:" OFFSTR : "=v"(dst) : "v"(addr))

#define RDA_LO(af, a) do { \
  DSR(af[0][0], a, "0");     DSR(af[0][1], a, "1024"); \
  DSR(af[1][0], a, "2048");  DSR(af[1][1], a, "3072"); \
  DSR(af[2][0], a, "4096");  DSR(af[2][1], a, "5120"); \
  DSR(af[3][0], a, "6144");  DSR(af[3][1], a, "7168"); } while (0)
#define RDA_HI(af, a) do { \
  DSR(af[0][0], a, "8192");  DSR(af[0][1], a, "9216"); \
  DSR(af[1][0], a, "10240"); DSR(af[1][1], a, "11264"); \
  DSR(af[2][0], a, "12288"); DSR(af[2][1], a, "13312"); \
  DSR(af[3][0], a, "14336"); DSR(af[3][1], a, "15360"); } while (0)
#define RDB_LO(bf, a) do { \
  DSR(bf[0][0], a, "0");    DSR(bf[0][1], a, "1024"); \
  DSR(bf[1][0], a, "2048"); DSR(bf[1][1], a, "3072"); } while (0)
#define RDB_HI(bf, a) do { \
  DSR(bf[2][0], a, "4096"); DSR(bf[2][1], a, "5120"); \
  DSR(bf[3][0], a, "6144"); DSR(bf[3][1], a, "7168"); } while (0)

// ---------------- prep: router + init + converts + transposes in ONE dispatch ----------------

__global__ void prep_kernel(const float* __restrict__ x,
                            const float* __restrict__ gw,
                            const float* __restrict__ bias,
                            const float* __restrict__ sw1,
                            const float* __restrict__ sw3,
                            const float* __restrict__ sw2,
                            const float* __restrict__ W1,
                            const float* __restrict__ W3,
                            const float* __restrict__ W2,
                            unsigned short* __restrict__ Xb,
                            unsigned short* __restrict__ sw1b,
                            unsigned short* __restrict__ sw3b,
                            unsigned short* __restrict__ sw2b,
                            unsigned short* __restrict__ W1t,
                            unsigned short* __restrict__ W3t,
                            unsigned short* __restrict__ W2t,
                            int* __restrict__ route_e,
                            float* __restrict__ route_w,
                            int* __restrict__ ptok) {
  __shared__ float tile[64][65];
  int bid = blockIdx.x;

  if (bid < O1) {
    // ---- router: 4 waves, 1 token each (fp64 to match numpy top-k exactly)
    int w = threadIdx.x >> 6, lane = threadIdx.x & 63;
    int t = bid * 4 + w;
    const float* xr = x + (long)t * Dm;
    double acc[En];
#pragma unroll
    for (int e = 0; e < En; e++) acc[e] = 0.0;
    for (int d = lane; d < Dm; d += 64) {
      double xv = (double)xr[d];
#pragma unroll
      for (int e = 0; e < En; e++) acc[e] += xv * (double)gw[e * Dm + d];
    }
#pragma unroll
    for (int off = 32; off > 0; off >>= 1) {
#pragma unroll
      for (int e = 0; e < En; e++) acc[e] += __shfl_down(acc[e], off);
    }
    if (lane == 0) {
      double sc[En], sel[En];
#pragma unroll
      for (int e = 0; e < En; e++) {
        sc[e] = 1.0 / (1.0 + exp(-acc[e]));
        sel[e] = sc[e] + (double)bias[e];
      }
      int i0 = 0;
#pragma unroll
      for (int e = 1; e < En; e++) if (sel[e] > sel[i0]) i0 = e;
      int i1 = (i0 == 0) ? 1 : 0;
#pragma unroll
      for (int e = 0; e < En; e++) if (e != i0 && sel[e] > sel[i1]) i1 = e;
      double s = sc[i0] + sc[i1];
      if (s < 1e-12) s = 1e-12;
      route_e[t * 2] = i0;  route_e[t * 2 + 1] = i1;
      route_w[t * 2] = (float)(sc[i0] / s);  route_w[t * 2 + 1] = (float)(sc[i1] / s);
    }
    return;
  }
  if (bid < O2) {
    // ---- init ptok (pad slots gather token 0)
    int i = (bid - O1) * 256 + threadIdx.x;
    if (i < CAP) ptok[i] = 0;
    return;
  }
  if (bid < O6) {
    // ---- flat fp32 -> bf16 converts
    const float* src; unsigned short* dst; int i;
    if (bid < O3)      { src = x;   dst = Xb;   i = (bid - O2) * 256 + threadIdx.x; }
    else if (bid < O4) { src = sw1; dst = sw1b; i = (bid - O3) * 256 + threadIdx.x; }
    else if (bid < O5) { src = sw3; dst = sw3b; i = (bid - O4) * 256 + threadIdx.x; }
    else               { src = sw2; dst = sw2b; i = (bid - O5) * 256 + threadIdx.x; }
    float4 v = ((const float4*)src)[i];
    union { unsigned short u[4]; unsigned long long ll; } p;
    p.u[0] = f2bf(v.x); p.u[1] = f2bf(v.y); p.u[2] = f2bf(v.z); p.u[3] = f2bf(v.w);
    *(unsigned long long*)(dst + (long)i * 4) = p.ll;
    return;
  }
  // ---- 64x64 transpose+convert of expert weights
  int tb = bid - O6;
  int z = tb / (TBZ * En);
  int rem = tb % (TBZ * En);
  int y = rem / TBZ;
  int xb = rem % TBZ;
  const float* s0; unsigned short* d0; int R, C;
  if (z == 0)      { s0 = W1; d0 = W1t; R = Dm; C = In; }
  else if (z == 1) { s0 = W3; d0 = W3t; R = Dm; C = In; }
  else             { s0 = W2; d0 = W2t; R = In; C = Dm; }
  int tilesC = C >> 6;
  int tr = (xb / tilesC) << 6;
  int tc = (xb % tilesC) << 6;
  const float* s = s0 + (long)y * R * C;
  unsigned short* d = d0 + (long)y * R * C;
  int rr = threadIdx.x >> 4, c4 = (threadIdx.x & 15) << 2;   // 16 rows x 16 float4
#pragma unroll
  for (int p = 0; p < 4; p++) {
    float4 v = *(const float4*)&s[(long)(tr + rr + 16 * p) * C + tc + c4];
    tile[rr + 16 * p][c4]     = v.x;
    tile[rr + 16 * p][c4 + 1] = v.y;
    tile[rr + 16 * p][c4 + 2] = v.z;
    tile[rr + 16 * p][c4 + 3] = v.w;
  }
  __syncthreads();
  int oc = threadIdx.x >> 5, i2 = (threadIdx.x & 31) << 1;   // 8 out-rows x 32 pairs
#pragma unroll
  for (int p = 0; p < 8; p++) {
    int j = oc + 8 * p;
    union { unsigned short u[2]; unsigned int w; } pk;
    pk.u[0] = f2bf(tile[i2][j]);
    pk.u[1] = f2bf(tile[i2 + 1][j]);
    *(unsigned int*)&d[(long)(tc + j) * R + tr + i2] = pk.w;
  }
}

// ---------------- offsets + scatter in one single-block kernel ----------------

__global__ void offscatter_kernel(const int* __restrict__ re,
                                  int* __restrict__ offs,
                                  int* __restrict__ ptok,
                                  int* __restrict__ pslot) {
  __shared__ int lcnt[En], loffs[En], lfill[En];
  int tid = threadIdx.x;
  if (tid < En) lcnt[tid] = 0;
  __syncthreads();
  for (int i = tid; i < Tn * 2; i += 1024) atomicAdd(&lcnt[re[i]], 1);
  __syncthreads();
  if (tid == 0) {
    int off = 0;
    for (int e = 0; e < En; e++) {
      loffs[e] = off; lfill[e] = off; offs[e] = off;
      off += (lcnt[e] + 255) & ~255;        // pad each expert segment to 256
    }
    offs[En] = off;
  }
  __syncthreads();
  for (int i = tid; i < Tn * 2; i += 1024) {
    int slot = atomicAdd(&lfill[re[i]], 1);
    ptok[slot] = i >> 1;
    pslot[i] = slot;                        // inverse map pair -> slot
  }
}

// ---------------- 8-phase 256-row GEMM core ----------------
// BM=256, BK=64, 512 threads = 8 waves (2M x 4N), per-wave C 128x64.
// LDS (dynamic 128KB): [buf0: A 32K | B 32K][buf1: A 32K | B 32K]
// st_16x32 XOR swizzle via pre-swizzled global source (linear gload_lds dest).

DEV void mm16(floatx4 (&acc)[8][4], const short8 (&af)[4][2],
              const short8 (&bf)[4][2], int mq, int nq) {
#pragma unroll
  for (int i = 0; i < 4; i++)
#pragma unroll
    for (int n = 0; n < 2; n++)
#pragma unroll
      for (int kk = 0; kk < 2; kk++)
        acc[4 * mq + i][2 * nq + n] = __builtin_amdgcn_mfma_f32_16x16x32_bf16(
            af[i][kk], bf[2 * nq + n][kk], acc[4 * mq + i][2 * nq + n], 0, 0, 0);
}

// chunk c (c = j*512 + tid) lands at linear LDS byte c*16; swizzled layout:
// row = (c>>7)*16 + ((c>>2)&15), colb = ((c>>6)&1)*64 + (((c&3)<<4) ^ (c&32 ? 32 : 0))
DEV void chunk_rc(int c, int& rowh, int& colb) {
  rowh = ((c >> 7) << 4) | ((c >> 2) & 15);
  colb = (((c >> 6) & 1) << 6) | ((((c & 3) << 4)) ^ ((c & 32) ? 32 : 0));
}

DEV void gemm_core(char* LDS, const char* (&gA)[2][2], const char* (&gB)[2][2],
                   floatx4 (&acc)[8][4], int NT, int wm, int wn, int wv, int aswz) {
  const int bsel = (wn >> 1) * 16384 + ((wn & 1) << 13);
  const int wb = wv * 1024;
  unsigned base = ldsoff(LDS);
  unsigned aA0 = base + wm * 16384 + aswz;
  unsigned aB0 = base + 32768 + bsel + aswz;
  unsigned aA1 = aA0 + 65536, aB1 = aB0 + 65536;
  // prologue: tile0 complete (8 loads) + tile1 j0 rounds A,B (4 loads)
  stg(gB[0][0], LDS + 32768 + wb);
  stg(gB[1][0], LDS + 32768 + 16384 + wb);
  stg(gB[0][1], LDS + 32768 + 8192 + wb);
  stg(gB[1][1], LDS + 32768 + 16384 + 8192 + wb);
  stg(gA[0][0], LDS + wb);
  stg(gA[1][0], LDS + 16384 + wb);
  stg(gA[0][1], LDS + 8192 + wb);
  stg(gA[1][1], LDS + 16384 + 8192 + wb);
  stg(gA[0][0] + 128, LDS + 65536 + wb);
  stg(gA[1][0] + 128, LDS + 65536 + 16384 + wb);
  stg(gB[0][0] + 128, LDS + 65536 + 32768 + wb);
  stg(gB[1][0] + 128, LDS + 65536 + 32768 + 16384 + wb);
  VMC(4);
  BARR();
  short8 af[4][2], bf[4][2];

  auto tile = [&](int t, int b, unsigned aA, unsigned aB) {
    char* An = LDS + ((b ^ 1) << 16);
    char* Bn = An + 32768;
    char* Ac = LDS + (b << 16);
    char* Bc = Ac + 32768;
    const int kn = (t + 1) << 7, ka = (t + 2) << 7;
    const bool s1 = (t + 1 < NT), s2 = (t + 2 < NT);
    // ---- phase 0: quadrant (mq0,nq0); stage B(t+1) j1
    RDA_LO(af, aA); RDB_LO(bf, aB);
    if (s1) { stg(gB[0][1] + kn, Bn + 8192 + wb);
              stg(gB[1][1] + kn, Bn + 16384 + 8192 + wb); }
    LGKM8(); BARR(); LGKM0(); PRIO(1); mm16(acc, af, bf, 0, 0); PRIO(0); BARR();
    // ---- phase 1: (mq0,nq1); stage A(t+1) j1
    RDB_HI(bf, aB);
    if (s1) { stg(gA[0][1] + kn, An + 8192 + wb);
              stg(gA[1][1] + kn, An + 16384 + 8192 + wb); }
    BARR(); LGKM0(); PRIO(1); mm16(acc, af, bf, 0, 1); PRIO(0); BARR();
    // ---- phase 2: (mq1,nq0); A-j0 of current buf dead -> stage A(t+2) j0
    RDA_HI(af, aA);
    if (s2) { stg(gA[0][0] + ka, Ac + wb);
              stg(gA[1][0] + ka, Ac + 16384 + wb); }
    BARR(); LGKM0(); PRIO(1); mm16(acc, af, bf, 1, 0); PRIO(0); BARR();
    // ---- phase 3: (mq1,nq1); B-j0 of current buf dead -> stage B(t+2) j0
    if (s2) { stg(gB[0][0] + ka, Bc + wb);
              stg(gB[1][0] + ka, Bc + 16384 + wb); }
    BARR(); LGKM0(); PRIO(1); mm16(acc, af, bf, 1, 1); PRIO(0);
    if (s2)      { VMC(4); }   // all of t+1 landed; t+2 j0 stays in flight
    else if (s1) { VMC(0); }   // pipeline drain near the end
    BARR();
  };
#pragma unroll 1
  for (int t2 = 0; t2 < NT; t2 += 2) {
    tile(t2, 0, aA0, aB0);
    tile(t2 + 1, 1, aA1, aB1);
  }
}

// ---------------- stage 1 (h): persistent merged kernel ----------------
// B tile interleaves W1/W3 in 32-row chunks; wave wn covers cols
// n0+wn*32..+31: acc[.][0..1]=h1 frags, acc[.][2..3]=h3 frags.

DEV void h_body(const unsigned short* Xb, const unsigned short* B1p,
                const unsigned short* B3p, unsigned short* ap, int Nact,
                int m0, int n0, const int* ptok, bool routed, char* LDS) {
  int tid = threadIdx.x, wv = tid >> 6, lane = tid & 63;
  int wm = wv >> 2, wn = wv & 3;
  int fr = lane & 15, fq = lane >> 4;
  int aswz = fr * 64 + ((fq * 16) ^ ((fr & 8) << 2));

  const char* gA[2][2]; const char* gB[2][2];
#pragma unroll
  for (int j = 0; j < 2; j++) {
    int rowh, colb;
    chunk_rc(j * 512 + tid, rowh, colb);
#pragma unroll
    for (int h = 0; h < 2; h++) {
      int grA = m0 + h * 128 + rowh;
      long ra = routed ? (long)ptok[grA] : (long)grA;
      gA[h][j] = (const char*)Xb + ra * (long)(Dm * 2) + colb;
      int rt = h * 128 + rowh;
      const unsigned short* src = ((rt >> 5) & 1) ? B3p : B1p;
      long rb = (long)n0 + ((rt >> 6) << 5) + (rt & 31);
      gB[h][j] = (const char*)src + rb * (long)(Dm * 2) + colb;
    }
  }
  floatx4 acc[8][4];
#pragma unroll
  for (int i = 0; i < 8; i++)
#pragma unroll
    for (int n = 0; n < 4; n++) acc[i][n] = (floatx4)0.0f;

  gemm_core(LDS, gA, gB, acc, Dm / 64, wm, wn, wv, aswz);

#pragma unroll
  for (int mi = 0; mi < 8; mi++)
#pragma unroll
    for (int n = 0; n < 2; n++)
#pragma unroll
      for (int r = 0; r < 4; r++) {
        int row = m0 + wm * 128 + mi * 16 + fq * 4 + r;
        int col = n0 + wn * 32 + n * 16 + fr;
        float h1 = acc[mi][n][r], h3 = acc[mi][n + 2][r];
        float v = h1 / (1.0f + __expf(-h1)) * h3;
        ap[(long)row * Nact + col] = f2bf(v);
      }
}

__global__ __launch_bounds__(512, 1)
void h_all(const unsigned short* __restrict__ Xb,
           const unsigned short* __restrict__ W1t,
           const unsigned short* __restrict__ W3t,
           const unsigned short* __restrict__ sw1b,
           const unsigned short* __restrict__ sw3b,
           unsigned short* __restrict__ act,
           unsigned short* __restrict__ actS,
           const int* __restrict__ ptok,
           const int* __restrict__ offs) {
  extern __shared__ char LDS[];
  const int Mr = offs[En] >> 8;             // live routed m-tiles
  const int RT = Mr * (In / 128);           // live routed tiles (no empties)
  const int TT = RT + SH_H;
  // XCD-chunked assignment: 32 same-XCD blocks walk a contiguous tile range
  const int per = (TT + 7) >> 3;
  const int xcd = blockIdx.x & 7, lix = blockIdx.x >> 3;
#pragma unroll 1
  for (int i = lix; i < per; i += 32) {
    int t = xcd * per + i;
    if (t >= TT) break;
    if (t < RT) {
      int m0 = (t % Mr) * 256, n0 = (t / Mr) * 128;
      int e = 0;
      while (!(m0 >= offs[e] && m0 < offs[e + 1])) e++;
      h_body(Xb, W1t + (long)e * In * Dm, W3t + (long)e * In * Dm,
             act, In, m0, n0, ptok, true, LDS);
    } else {
      int u = t - RT;
      int m0 = (u & 15) * 256, n0 = (u >> 4) * 128;
      h_body(Xb, sw1b, sw3b, actS, SIn, m0, n0, nullptr, false, LDS);
    }
  }
}

// ---------------- stage 2 (o): persistent merged kernel ----------------

DEV void o_core(const unsigned short* Apt, const unsigned short* Bpt,
                int lda, int ldb, int NT, int m0, int n0,
                floatx4 (&acc)[8][4], char* LDS) {
  int tid = threadIdx.x, wv = tid >> 6, lane = tid & 63;
  int wm = wv >> 2, wn = wv & 3;
  int fr = lane & 15, fq = lane >> 4;
  int aswz = fr * 64 + ((fq * 16) ^ ((fr & 8) << 2));

  const char* gA[2][2]; const char* gB[2][2];
#pragma unroll
  for (int j = 0; j < 2; j++) {
    int rowh, colb;
    chunk_rc(j * 512 + tid, rowh, colb);
#pragma unroll
    for (int h = 0; h < 2; h++) {
      gA[h][j] = (const char*)Apt + (long)(m0 + h * 128 + rowh) * (lda * 2) + colb;
      gB[h][j] = (const char*)Bpt + (long)(n0 + h * 128 + rowh) * (ldb * 2) + colb;
    }
  }
#pragma unroll
  for (int i = 0; i < 8; i++)
#pragma unroll
    for (int n = 0; n < 4; n++) acc[i][n] = (floatx4)0.0f;

  gemm_core(LDS, gA, gB, acc, NT, wm, wn, wv, aswz);
}

__global__ __launch_bounds__(512, 1)
void o_all(const unsigned short* __restrict__ act,
           const unsigned short* __restrict__ actS,
           const unsigned short* __restrict__ W2t,
           const unsigned short* __restrict__ sw2b,
           unsigned short* __restrict__ yR,
           float* __restrict__ out,
           const int* __restrict__ offs) {
  extern __shared__ char LDS[];
  const int Mr = offs[En] >> 8;
  const int RT = Mr * (Dm / 256);           // live routed o tiles
  const int TT = SH_O + RT;                 // shared tiles FIRST (longest jobs)
  int lane = threadIdx.x & 63, wv = threadIdx.x >> 6;
  int wm = wv >> 2, wn = wv & 3;
  int fr = lane & 15, fq = lane >> 4;
  const int per = (TT + 7) >> 3;
  const int xcd = blockIdx.x & 7, lix = blockIdx.x >> 3;
#pragma unroll 1
  for (int i = lix; i < per; i += 32) {
    int t = xcd * per + i;
    if (t >= TT) break;
    floatx4 acc[8][4];
    if (t >= SH_O) {
      int u = t - SH_O;
      int m0 = (u % Mr) * 256, n0 = (u / Mr) * 256;
      int e = 0;
      while (!(m0 >= offs[e] && m0 < offs[e + 1])) e++;
      o_core(act, W2t + (long)e * Dm * In, In, In, In / 64, m0, n0, acc, LDS);
#pragma unroll
      for (int mi = 0; mi < 8; mi++)
#pragma unroll
        for (int r = 0; r < 4; r++) {
          int row = m0 + wm * 128 + mi * 16 + fq * 4 + r;
#pragma unroll
          for (int ni = 0; ni < 4; ni++) {
            int col = n0 + wn * 64 + ni * 16 + fr;
            yR[(long)row * Dm + col] = f2bf(acc[mi][ni][r]);
          }
        }
    } else {
      int u = t;
      int m0 = (u & 15) * 256, n0 = (u >> 4) * 256;
      o_core(actS, sw2b, SIn, SIn, SIn / 64, m0, n0, acc, LDS);
#pragma unroll
      for (int mi = 0; mi < 8; mi++)
#pragma unroll
        for (int r = 0; r < 4; r++) {
          int row = m0 + wm * 128 + mi * 16 + fq * 4 + r;
#pragma unroll
          for (int ni = 0; ni < 4; ni++) {
            int col = n0 + wn * 64 + ni * 16 + fr;
            out[(long)row * Dm + col] = acc[mi][ni][r];
          }
        }
    }
  }
}

// ---------------- combine: out[t] += w0*yR[s0] + w1*yR[s1] ----------------

__global__ void combine_kernel(const unsigned short* __restrict__ yR,
                               const int* __restrict__ pslot,
                               const float* __restrict__ rw,
                               float* __restrict__ out) {
  int idx = blockIdx.x * 256 + threadIdx.x;   // Tn * (Dm/4) threads
  int t = idx >> 9, c4 = idx & 511;           // Dm/4 = 512
  int s0 = pslot[t * 2], s1 = pslot[t * 2 + 1];
  float w0 = rw[t * 2], w1 = rw[t * 2 + 1];
  ushort4 a = ((const ushort4*)(yR + (long)s0 * Dm))[c4];
  ushort4 b = ((const ushort4*)(yR + (long)s1 * Dm))[c4];
  float4* op = (float4*)(out + (long)t * Dm) + c4;
  float4 o = *op;
  o.x += w0 * bf2f(a.x) + w1 * bf2f(b.x);
  o.y += w0 * bf2f(a.y) + w1 * bf2f(b.y);
  o.z += w0 * bf2f(a.z) + w1 * bf2f(b.z);
  o.w += w0 * bf2f(a.w) + w1 * bf2f(b.w);
  *op = o;
}

// ---------------- launch ----------------

extern "C" void kernel_launch(void* const* d_in, const int* in_sizes, int n_in,
                              void* d_out, int out_size, void* d_ws, size_t ws_size,
                              hipStream_t stream) {
  const float* x    = (const float*)d_in[0];
  const float* gw   = (const float*)d_in[1];
  const float* bias = (const float*)d_in[2];
  const float* W1   = (const float*)d_in[3];
  const float* W3   = (const float*)d_in[4];
  const float* W2   = (const float*)d_in[5];
  const float* sw1  = (const float*)d_in[6];
  const float* sw3  = (const float*)d_in[7];
  const float* sw2  = (const float*)d_in[8];
  float* out = (float*)d_out;

  static bool attr_done = false;
  if (!attr_done) {
    hipFuncSetAttribute(reinterpret_cast<const void*>(h_all),
                        hipFuncAttributeMaxDynamicSharedMemorySize, 131072);
    hipFuncSetAttribute(reinterpret_cast<const void*>(o_all),
                        hipFuncAttributeMaxDynamicSharedMemorySize, 131072);
    attr_done = true;
  }

  char* p = (char*)d_ws;
  auto alloc = [&](size_t bytes) {
    char* r = p; p += (bytes + 255) & ~(size_t)255; return r;
  };
  unsigned short* Xb   = (unsigned short*)alloc((size_t)Tn * Dm * 2);
  unsigned short* W1t  = (unsigned short*)alloc((size_t)En * In * Dm * 2);
  unsigned short* W3t  = (unsigned short*)alloc((size_t)En * In * Dm * 2);
  unsigned short* W2t  = (unsigned short*)alloc((size_t)En * Dm * In * 2);
  unsigned short* sw1b = (unsigned short*)alloc((size_t)SIn * Dm * 2);
  unsigned short* sw3b = (unsigned short*)alloc((size_t)SIn * Dm * 2);
  unsigned short* sw2b = (unsigned short*)alloc((size_t)Dm * SIn * 2);
  unsigned short* act  = (unsigned short*)alloc((size_t)CAP * In * 2);
  unsigned short* actS = (unsigned short*)alloc((size_t)Tn * SIn * 2);
  unsigned short* yR   = (unsigned short*)alloc((size_t)CAP * Dm * 2);
  int*   route_e = (int*)alloc(Tn * 2 * 4);
  float* route_w = (float*)alloc(Tn * 2 * 4);
  int*   offs    = (int*)alloc(256);
  int*   ptok    = (int*)alloc(CAP * 4);
  int*   pslot   = (int*)alloc(Tn * 2 * 4);

  // 1) all conversions + transposes + router in one dispatch
  prep_kernel<<<PREP_B, 256, 0, stream>>>(
      x, gw, bias, sw1, sw3, sw2, W1, W3, W2,
      Xb, sw1b, sw3b, sw2b, W1t, W3t, W2t, route_e, route_w, ptok);

  // 2) offsets + scatter (single block, LDS counters)
  offscatter_kernel<<<1, 1024, 0, stream>>>(route_e, offs, ptok, pslot);

  // 3) persistent GEMM stages (256 blocks = 1/CU, 128KB dynamic LDS each)
  h_all<<<NBLK, 512, 131072, stream>>>(Xb, W1t, W3t, sw1b, sw3b, act, actS, ptok, offs);
  o_all<<<NBLK, 512, 131072, stream>>>(act, actS, W2t, sw2b, yR, out, offs);

  // 4) weighted combine
  combine_kernel<<<Tn * (Dm / 4) / 256, 256, 0, stream>>>(yR, pslot, route_w, out);
}